// Round 20
// baseline (28.278 us; speedup 1.0000x reference)
//
#include <hip/hip_runtime.h>

// QuanvolutionSelfAttentionClassifier on MI355X — round 20: depth-2 A +
// depth-1 B register prefetch on the R19 structure.
//
// Algebra (verified R1-R19): softmax over length-1 axis == 1 ->
// attn_weights == mean_embeds (rotation/entangle dead). l = c*196+p ->
// d = p&3; pixel (r,cc): d = (2*((r>>1)&1) + (cc>>1)) & 3.
//   logits[j] = lin_b[j] + sum_d M[d]*(cst[d][j] + T[d][j])
//   M[d] = a + sum_pix x*gm,  T[d][j] = sum_{pix in d} x*G[pix][j]
// Y = X·G via mfma_f32_16x16x32_bf16 (single RNE bf16, err ~3e-3 << margin);
// col = d*12+j; zero-redundancy A k-map (R19): (kb,e) -> k = t*32 + kb*4 +
// (e>=4?16:0) + (e&3); C layout col=lane&15, row=(lane>>4)*4+reg (verified 8x).
//
// R19 (+1.3us) validated the transaction model again. Remaining stall by
// arithmetic: ~170cy work/iter vs ~500cy load latency at depth-1 prefetch,
// in-flight 16KB/CU vs ~12.3KB needed — no jitter headroom; B ds_reads add
// ~120cy lgkmcnt on the critical path. v20: depth-2 A-prefetch (in-flight
// 32KB/CU) + depth-1 B-register prefetch (lgkmcnt overlaps MFMA), unroll-2
// body, all named regs. R14's depth null was a different regime (8 waves,
// 16x16 pre-remap) — retested here per the regime-gate rule.

typedef __attribute__((ext_vector_type(8))) short bf16x8;
typedef __attribute__((ext_vector_type(4))) float f32x4;
typedef __attribute__((ext_vector_type(4))) unsigned int uint4v;

union BU { uint4v u; bf16x8 b; };
union AB { unsigned int u[4]; bf16x8 b; };

__device__ __forceinline__ unsigned rne16(float f) {
  const unsigned u = __float_as_uint(f);
  return (u + 0x7FFFu + ((u >> 16) & 1u)) >> 16;
}

#define CST_F 19200   // float idx in ws (after 38400 shorts): cst[40]
#define A_F   19240   // float idx: a

// prep: B-image bf16, BYTE-IDENTICAL to main's LDS layout (R19-verified).
// i -> e=i&7, ln=(i>>3)&63, c=i>>9 (c = t*3+nt, 0..74);
// col=(c%3)*16+(ln&15); k = t*32 + (ln>>4)*4 + (e>=4?16:0) + (e&3).
__global__ void qsac_prep(const float* __restrict__ cw, const float* __restrict__ cb,
                          const float* __restrict__ lw, float* __restrict__ wsf) {
  __shared__ float cpart[200];
  unsigned short* gt = (unsigned short*)wsf;
  const int i = blockIdx.x * 256 + threadIdx.x;  // 150 x 256 = 38400
  const int e = i & 7, ln = (i >> 3) & 63, c = i >> 9;
  const int t = c / 3, nt = c - t * 3;
  const int col = nt * 16 + (ln & 15);
  const int k = t * 32 + ((ln >> 4) << 2) + ((e >> 2) << 4) + (e & 3);
  float val = 0.f;
  if (k < 784) {
    const int r = k / 28, cc = k - r * 28;
    const int kh = r & 1, kw = cc & 1;
    const int p = (r >> 1) * 14 + (cc >> 1);
    const int dpix = (2 * ((r >> 1) & 1) + (cc >> 1)) & 3;
    const int cd = col / 12, cj = col - cd * 12;
    if (cd == dpix) {
      const float w0 = cw[(kh << 1) + kw],     w1 = cw[4 + (kh << 1) + kw],
                  w2 = cw[8 + (kh << 1) + kw], w3 = cw[12 + (kh << 1) + kw];
      if (cj < 10)
        val = w0 * lw[cj * 784 + p]       + w1 * lw[cj * 784 + 196 + p] +
              w2 * lw[cj * 784 + 392 + p] + w3 * lw[cj * 784 + 588 + p];
      else if (cj == 10)
        val = (w0 + w1 + w2 + w3) * (1.0f / 196.0f);
    }
  }
  gt[c * 512 + ln * 8 + e] = (unsigned short)rne16(val);

  if (blockIdx.x == 0) {
    const int u = threadIdx.x;
    if (u < 200) {
      const int g = u / 5, ch = u - (u / 5) * 5;
      const int d = g / 10, j = g - (g / 10) * 10;
      const float b0 = cb[0], b1 = cb[1], b2 = cb[2], b3 = cb[3];
      float s = 0.f;
#pragma unroll
      for (int n = 0; n < 10; ++n) {
        const int pi = ch + 5 * n;
        if (pi < 49) {
          const int q = d + 4 * pi;
          s += b0 * lw[j * 784 + q]       + b1 * lw[j * 784 + 196 + q] +
               b2 * lw[j * 784 + 392 + q] + b3 * lw[j * 784 + 588 + q];
        }
      }
      cpart[u] = s;
    }
    __syncthreads();
    if (u < 40) {
      float s = 0.f;
#pragma unroll
      for (int ch = 0; ch < 5; ++ch) s += cpart[u * 5 + ch];
      wsf[CST_F + u] = s;
    } else if (u == 40) {
      wsf[A_F] = (cb[0] + cb[1] + cb[2] + cb[3]) * 0.25f;
    }
  }
}

__global__ __launch_bounds__(512)
__attribute__((amdgpu_waves_per_eu(4, 4))) void qsac_main(
    const float* __restrict__ x, const float* __restrict__ wsf,
    const float* __restrict__ lin_b, float* __restrict__ out) {
  // B in LDS: chunk c (=t*3+nt): 16B/lane at byte c*1024 + lane*16.
  __shared__ unsigned int smemu[19200];  // 76,800 B -> 2 blocks/CU

  const int tid = threadIdx.x;
  const int lane = tid & 63;
  const int wid = __builtin_amdgcn_readfirstlane(tid >> 6);  // 0..7
  const int strip = wid & 3;    // 4 strips x 16 samples = 64 samples/block
  const int khalf = wid >> 2;   // 0: tiles [0,12); 1: tiles [12,25)
  const int nn = lane & 15, kb = lane >> 4;
  const int sbase = blockIdx.x * 64 + strip * 16;
  const float* xrow = x + (size_t)(sbase + nn) * 784;

  // ---- B staging: pure 16B global_load_lds copy of the ws image.
  {
    const char* wsb = (const char*)wsf;
#pragma unroll
    for (int i = 0; i < 10; ++i) {
      const int c = i * 8 + wid;
      if (c < 75) {
        __builtin_amdgcn_global_load_lds(
            (const __attribute__((address_space(1))) unsigned int*)
                (wsb + (size_t)(c * 64 + lane) * 16),
            (__attribute__((address_space(3))) unsigned int*)&smemu[c * 256],
            16, 0, 0);
      }
    }
  }
  __syncthreads();  // drains vmcnt -> B image complete

  f32x4 acc[3];
#pragma unroll
  for (int nt = 0; nt < 3; ++nt) acc[nt] = (f32x4){0.f, 0.f, 0.f, 0.f};

  auto ldB = [&](int t, BU (&bh)[3]) {
    const unsigned int* bb = smemu + t * 768 + lane * 4;
#pragma unroll
    for (int nt = 0; nt < 3; ++nt) bh[nt].u = *(const uint4v*)(bb + nt * 256);
  };
  auto tile = [&](const float4& a, const float4& b2, const BU (&bh)[3]) {
    AB Ah;
    Ah.u[0] = rne16(a.x)  | (rne16(a.y)  << 16);
    Ah.u[1] = rne16(a.z)  | (rne16(a.w)  << 16);
    Ah.u[2] = rne16(b2.x) | (rne16(b2.y) << 16);
    Ah.u[3] = rne16(b2.z) | (rne16(b2.w) << 16);
#pragma unroll
    for (int nt = 0; nt < 3; ++nt)
      acc[nt] = __builtin_amdgcn_mfma_f32_16x16x32_bf16(Ah.b, bh[nt].b, acc[nt], 0, 0, 0);
  };
  // Zero-redundancy A lines (R19): elems 0-3 at k=t*32+kb*4 (one 64B line
  // per row across the 4 kb-lanes), elems 4-7 at +16 floats (next line).
  // Tail t=24: elems 4-7 are k>=784 -> B rows zero -> clamp address.
  auto ldA = [&](int t, float4& a, float4& b2) {
    const float* p = xrow + t * 32 + kb * 4;
    a = *(const float4*)p;
    const float* p2 = (t < 24) ? (p + 16) : xrow;
    b2 = *(const float4*)p2;
  };

  // K-half [t0, t1): 12 or 13 tiles. Depth-2 A ring (xa0/xa1 loaded 2 tiles
  // ahead) + depth-1 B regs (bc current, bn next), unroll-2 body.
  const int t0 = khalf ? 12 : 0;
  const int t1 = khalf ? 25 : 12;
  float4 xa0, xb0, xa1, xb1;
  BU bc[3], bn[3];
  ldA(t0, xa0, xb0);
  ldA(t0 + 1, xa1, xb1);
  ldB(t0, bc);
#pragma unroll 1
  for (int tt = 0; tt < 6; ++tt) {
    const int t = t0 + tt * 2;
    ldB(t + 1, bn);                       // next B -> regs (lgkm overlaps MFMA)
    tile(xa0, xb0, bc);                   // compute tile t
    if (t + 2 < t1) {
      ldA(t + 2, xa0, xb0);               // A depth-2 refill
      ldB(t + 2, bc);                     // B for tile t+2 (bc free now)
    }
    tile(xa1, xb1, bn);                   // compute tile t+1
    if (t + 3 < t1) ldA(t + 3, xa1, xb1); // A depth-2 refill
  }
  if (khalf) tile(xa0, xb0, bc);          // tile 24 (A/B prefetched in-loop)

  // ---- pair-reduction + epilogue in dead-B LDS (R17/R19-verified) ----
  __syncthreads();  // all waves past the loop -> B truly dead
  float* red = (float*)smemu;                   // [4 strips][64 lanes][12]
  if (khalf == 1) {
#pragma unroll
    for (int nt = 0; nt < 3; ++nt)
#pragma unroll
      for (int rg = 0; rg < 4; ++rg)
        red[(strip * 64 + lane) * 12 + nt * 4 + rg] = acc[nt][rg];
  }
  __syncthreads();
  if (khalf == 0) {
#pragma unroll
    for (int nt = 0; nt < 3; ++nt)
#pragma unroll
      for (int rg = 0; rg < 4; ++rg)
        acc[nt][rg] += red[(strip * 64 + lane) * 12 + nt * 4 + rg];

    // C exchange (after the reduction area) + per-sample finish.
    float* cx = (float*)smemu + 3072 + strip * (16 * 52);
#pragma unroll
    for (int nt = 0; nt < 3; ++nt)
#pragma unroll
      for (int rg = 0; rg < 4; ++rg)
        cx[(kb * 4 + rg) * 52 + nt * 16 + nn] = acc[nt][rg];
    __builtin_amdgcn_wave_barrier();  // same-wave LDS pipe is in-order

    if (lane < 16) {
      float Y[48];
#pragma unroll
      for (int q = 0; q < 12; ++q) {
        const float4 t4 = *(const float4*)&cx[lane * 52 + q * 4];
        Y[q * 4 + 0] = t4.x; Y[q * 4 + 1] = t4.y;
        Y[q * 4 + 2] = t4.z; Y[q * 4 + 3] = t4.w;
      }
      const float a = wsf[A_F];
      float M[4];
#pragma unroll
      for (int d = 0; d < 4; ++d) M[d] = a + Y[d * 12 + 10];
      float logits[10];
#pragma unroll
      for (int j = 0; j < 10; ++j) {
        float vv = lin_b[j];
#pragma unroll
        for (int d = 0; d < 4; ++d)
          vv += M[d] * (wsf[CST_F + d * 10 + j] + Y[d * 12 + j]);
        logits[j] = vv;
      }
      float mx = logits[0];
#pragma unroll
      for (int j = 1; j < 10; ++j) mx = fmaxf(mx, logits[j]);
      float se = 0.f;
#pragma unroll
      for (int j = 0; j < 10; ++j) se += __expf(logits[j] - mx);
      const float lse = mx + __logf(se);
      float* op = out + (size_t)(sbase + lane) * 10;
#pragma unroll
      for (int j = 0; j < 10; ++j) op[j] = logits[j] - lse;
    }
  }
}

extern "C" void kernel_launch(void* const* d_in, const int* in_sizes, int n_in,
                              void* d_out, int out_size, void* d_ws, size_t ws_size,
                              hipStream_t stream) {
  (void)n_in; (void)ws_size; (void)out_size;
  const float* x = (const float*)d_in[0];
  const float* conv_w = (const float*)d_in[1];
  const float* conv_b = (const float*)d_in[2];
  // d_in[3]/d_in[4] (rotation/entangle) are dead: softmax over length-1 == 1.
  const float* lin_w = (const float*)d_in[5];
  const float* lin_b = (const float*)d_in[6];
  float* out = (float*)d_out;
  float* wsf = (float*)d_ws;

  hipLaunchKernelGGL(qsac_prep, dim3(150), dim3(256), 0, stream,
                     conv_w, conv_b, lin_w, wsf);

  const int B = in_sizes[0] / 784;  // 32768
  const int nblk = B / 64;          // 512 blocks x 512 threads (2 blocks/CU)
  hipLaunchKernelGGL(qsac_main, dim3(nblk), dim3(512), 0, stream,
                     x, wsf, lin_b, out);
}